// Round 4
// baseline (2546.435 us; speedup 1.0000x reference)
//
#include <hip/hip_runtime.h>
#include <math.h>

#define NBINS   16384
#define GB_HIST 128
#define GBC     256     // count/scatter grid blocks
#define CAP     2048
#define DCH     64
#define NBMAX   1024    // max buckets (N <= 65536)
#define SCAN_CH 2048

struct Ctrl {
    double thr;
    int cand_cnt;
    int b0, b1;
    int base0;
    float s0, s1;
};

__device__ __forceinline__ int bin_of(float v) {
    int b = (int)(v * (float)NBINS);
    if (b < 0) b = 0;
    if (b >= NBINS) b = NBINS - 1;
    return b;
}

// ---------- LDS histogram, dense (non-atomic) flush ----------
__global__ void k_hist(const float* __restrict__ att, int E, int* __restrict__ hist2d) {
    __shared__ int lh[NBINS];   // 64 KB
    int t = threadIdx.x;
    for (int b = t; b < NBINS; b += 256) lh[b] = 0;
    __syncthreads();
    for (int i = blockIdx.x * 256 + t; i < E; i += GB_HIST * 256)
        atomicAdd(&lh[bin_of(att[i])], 1);
    __syncthreads();
    for (int b = t; b < NBINS; b += 256)
        hist2d[blockIdx.x * NBINS + b] = lh[b];
}

// 64 blocks x 256: fold 128 partial hists, emit per-256-bin-chunk sums
__global__ void k_fold(const int* __restrict__ hist2d, int* __restrict__ hist,
                       int* __restrict__ csum) {
    __shared__ int sh[4];
    int t = threadIdx.x;
    int j = blockIdx.x * 256 + t;
    int s = 0;
    for (int k = 0; k < GB_HIST; k++) s += hist2d[k * NBINS + j];
    hist[j] = s;
    int r = s;
    for (int off = 32; off > 0; off >>= 1) r += __shfl_down(r, off, 64);
    if ((t & 63) == 0) sh[t >> 6] = r;
    __syncthreads();
    if (t == 0) csum[blockIdx.x] = sh[0] + sh[1] + sh[2] + sh[3];
}

// 1 block: chunk scan (64 chunks) then bin scans -> b0, b1, base0
__global__ void k_pick(const int* __restrict__ hist, const int* __restrict__ csum,
                       Ctrl* ctrl, long long i0, long long i1) {
    __shared__ int sh[256];
    __shared__ int c0s, c1s;
    __shared__ long long e0s, e1s;
    int t = threadIdx.x;
    int v = (t < 64) ? csum[t] : 0;
    sh[t] = v;
    __syncthreads();
    for (int off = 1; off < 256; off <<= 1) {
        int u = (t >= off) ? sh[t - off] : 0;
        __syncthreads(); sh[t] += u; __syncthreads();
    }
    long long excl = (long long)(sh[t] - v);
    if (t < 64) {
        if (i0 >= excl && i0 < excl + v) { c0s = t; e0s = excl; }
        if (i1 >= excl && i1 < excl + v) { c1s = t; e1s = excl; }
    }
    __syncthreads();
    int c0 = c0s, c1 = c1s;
    long long e0 = e0s, e1 = e1s;

    int hv = hist[c0 * 256 + t];
    sh[t] = hv; __syncthreads();
    for (int off = 1; off < 256; off <<= 1) {
        int u = (t >= off) ? sh[t - off] : 0;
        __syncthreads(); sh[t] += u; __syncthreads();
    }
    long long be = e0 + (long long)(sh[t] - hv);
    if (i0 >= be && i0 < be + hv) { ctrl->b0 = c0 * 256 + t; ctrl->base0 = (int)be; }
    __syncthreads();

    hv = hist[c1 * 256 + t];
    sh[t] = hv; __syncthreads();
    for (int off = 1; off < 256; off <<= 1) {
        int u = (t >= off) ? sh[t - off] : 0;
        __syncthreads(); sh[t] += u; __syncthreads();
    }
    be = e1 + (long long)(sh[t] - hv);
    if (i1 >= be && i1 < be + hv) { ctrl->b1 = c1 * 256 + t; }
}

__global__ void k_collect(const float* __restrict__ att, int E,
                          Ctrl* ctrl, float* __restrict__ cand) {
    int b0 = ctrl->b0, b1 = ctrl->b1;
    int i = blockIdx.x * blockDim.x + threadIdx.x;
    int stride = gridDim.x * blockDim.x;
    for (; i < E; i += stride) {
        float v = att[i];
        int b = bin_of(v);
        if (b >= b0 && b <= b1) {
            int idx = atomicAdd(&ctrl->cand_cnt, 1);
            if (idx < CAP) cand[idx] = v;
        }
    }
}

__global__ void k_finalize(Ctrl* ctrl, const float* __restrict__ cand,
                           long long i0, long long i1, double frac) {
    __shared__ float sh[CAP];
    __shared__ float s0s, s1s;
    int n = ctrl->cand_cnt;
    if (n > CAP) n = CAP;
    for (int i = threadIdx.x; i < n; i += blockDim.x) sh[i] = cand[i];
    __syncthreads();
    int r0 = (int)(i0 - (long long)ctrl->base0);
    int r1 = (int)(i1 - (long long)ctrl->base0);
    for (int i = threadIdx.x; i < n; i += blockDim.x) {
        float v = sh[i];
        int rank = 0;
        for (int j = 0; j < n; j++) {
            float u = sh[j];
            rank += (u < v) || (u == v && j < i);
        }
        if (rank == r0) s0s = v;
        if (rank == r1) s1s = v;
    }
    __syncthreads();
    if (threadIdx.x == 0) {
        double a = (double)s0s, b = (double)s1s;
        ctrl->thr = b - (b - a) * (1.0 - frac);   // numpy _lerp, t>=0.5 branch
        ctrl->s0 = s0s; ctrl->s1 = s1s;
    }
}

// ---------- count pass: LDS bucket counters for dst AND src, dense flush ----------
__global__ void k_count(const float* __restrict__ att, const int* __restrict__ src,
                        const int* __restrict__ dst, int E, int NB, int NB256,
                        const Ctrl* __restrict__ ctrl, int* __restrict__ cntAll) {
    __shared__ int lD[NBMAX], lS[NBMAX];
    int t = threadIdx.x;
    for (int b = t; b < NB; b += 256) { lD[b] = 0; lS[b] = 0; }
    __syncthreads();
    double thr = ctrl->thr;
    for (int i = blockIdx.x * 256 + t; i < E; i += GBC * 256) {
        float v = att[i];
        if ((double)v > thr) {
            atomicAdd(&lD[dst[i] >> 6], 1);
            atomicAdd(&lS[src[i] >> 6], 1);
        }
    }
    __syncthreads();
    for (int b = t; b < NB; b += 256) {
        cntAll[blockIdx.x * NB + b]         = lD[b];
        cntAll[NB256 + blockIdx.x * NB + b] = lS[b];
    }
}

// scan domain j in [0, 2*NB256): (half, bucket, blk) -> cntAll[half*NB256 + blk*NB + bucket]
__device__ __forceinline__ int cnt_at(const int* cntAll, int j, int NB, int NB256) {
    int base = 0, r = j;
    if (j >= NB256) { base = NB256; r = j - NB256; }
    return cntAll[base + (r & 255) * NB + (r >> 8)];
}

__global__ void k_scan1(const int* __restrict__ cntAll, int NB, int NB256, int NK2,
                        int* __restrict__ bsum) {
    __shared__ int sh[8];
    int b = blockIdx.x, t = threadIdx.x;
    int j0 = b * SCAN_CH + t * 8;
    int s = 0;
    for (int u = 0; u < 8; u++) {
        int j = j0 + u;
        if (j < NK2) s += cnt_at(cntAll, j, NB, NB256);
    }
    for (int off = 32; off > 0; off >>= 1) s += __shfl_down(s, off, 64);
    if ((t & 63) == 0) sh[t >> 6] = s;
    __syncthreads();
    if (t == 0) bsum[b] = sh[0] + sh[1] + sh[2] + sh[3];
}

__global__ void k_scan2(const int* __restrict__ bsum, int nb,
                        int* __restrict__ boff, int* __restrict__ off2d, int NK2) {
    __shared__ int sh[256];
    int t = threadIdx.x;
    int v = (t < nb) ? bsum[t] : 0;
    sh[t] = v;
    __syncthreads();
    for (int off = 1; off < 256; off <<= 1) {
        int u = (t >= off) ? sh[t - off] : 0;
        __syncthreads(); sh[t] += u; __syncthreads();
    }
    boff[t] = sh[t] - v;
    if (t == 255) off2d[NK2] = sh[255];
}

__global__ void k_scan3(const int* __restrict__ cntAll, int NB, int NB256, int NK2,
                        const int* __restrict__ boff, int* __restrict__ off2d) {
    __shared__ int sh[256];
    int b = blockIdx.x, t = threadIdx.x;
    int j0 = b * SCAN_CH + t * 8;
    int v[8];
    int ts = 0;
    for (int u = 0; u < 8; u++) {
        int j = j0 + u;
        v[u] = (j < NK2) ? cnt_at(cntAll, j, NB, NB256) : 0;
        ts += v[u];
    }
    sh[t] = ts;
    __syncthreads();
    for (int off = 1; off < 256; off <<= 1) {
        int u = (t >= off) ? sh[t - off] : 0;
        __syncthreads(); sh[t] += u; __syncthreads();
    }
    int excl = boff[b] + sh[t] - ts;
    for (int u = 0; u < 8; u++) {
        int j = j0 + u;
        if (j < NK2) off2d[j] = excl;
        excl += v[u];
    }
}

// ---------- scatter into dst-bucketed (src|dlow, v) and src-bucketed (v, slow) ----------
__global__ void k_scatter(const float* __restrict__ att, const int* __restrict__ src,
                          const int* __restrict__ dst, int E, int NB, int NB256,
                          const Ctrl* __restrict__ ctrl, const int* __restrict__ off2d,
                          uint2* __restrict__ ebufD, float* __restrict__ ebufSv,
                          unsigned char* __restrict__ ebufSs) {
    __shared__ int baseD[NBMAX], baseS[NBMAX], fD[NBMAX], fS[NBMAX];
    int t = threadIdx.x;
    int K = off2d[NB256];
    for (int b = t; b < NB; b += 256) {
        baseD[b] = off2d[b * 256 + blockIdx.x];
        baseS[b] = off2d[NB256 + b * 256 + blockIdx.x] - K;
        fD[b] = 0; fS[b] = 0;
    }
    __syncthreads();
    double thr = ctrl->thr;
    for (int i = blockIdx.x * 256 + t; i < E; i += GBC * 256) {
        float v = att[i];
        if ((double)v > thr) {
            int s = src[i], d = dst[i];
            int bD = d >> 6, bS = s >> 6;
            int pD = baseD[bD] + atomicAdd(&fD[bD], 1);
            uint2 ev; ev.x = (unsigned)s | ((unsigned)(d & 63) << 16);
            ev.y = __float_as_uint(v);
            ebufD[pD] = ev;
            int pS = baseS[bS] + atomicAdd(&fS[bS], 1);
            ebufSv[pS] = v;
            ebufSs[pS] = (unsigned char)(s & 63);
        }
    }
}

// per-src-bucket segment sum -> sums[N]
__global__ void k_sums(const int* __restrict__ off2d, int NB256,
                       const float* __restrict__ ebufSv, const unsigned char* __restrict__ ebufSs,
                       float* __restrict__ sums, int N) {
    __shared__ float s64[64];
    int b = blockIdx.x, t = threadIdx.x;
    if (t < 64) s64[t] = 0.f;
    __syncthreads();
    int K = off2d[NB256];
    int lo = off2d[NB256 + b * 256] - K;
    int hi = off2d[NB256 + (b + 1) * 256] - K;
    for (int e = lo + t; e < hi; e += 256)
        atomicAdd(&s64[ebufSs[e]], ebufSv[e]);
    __syncthreads();
    if (t < 64) {
        int node = b * 64 + t;
        if (node < N) sums[node] = s64[t];
    }
}

// rewrite ebufD weight: v -> v / (sums[src]+eps)
__global__ void k_wfix(uint2* __restrict__ ebufD, const float* __restrict__ sums,
                       const int* __restrict__ off2d, int NB256) {
    int K = off2d[NB256];
    int i = blockIdx.x * 256 + threadIdx.x;
    if (i >= K) return;
    uint2 ev = ebufD[i];
    int s = ev.x & 0xFFFF;
    float v = __uint_as_float(ev.y) / (sums[s] + 1e-16f);
    ebufD[i].y = __float_as_uint(v);
}

// ---------- spmv: one block per dst bucket, LDS az[64 nodes][64 ch], ds_add ----------
__global__ __launch_bounds__(256) void k_spmv(
    const int* __restrict__ off2d, const uint2* __restrict__ ebufD,
    const float* __restrict__ zin, const float* __restrict__ x,
    float* __restrict__ acc, float* __restrict__ zout, int N, int pass)
{
    __shared__ float az[64 * 64];
    int b = blockIdx.x;
    int lane = threadIdx.x;   // 0..63 = channel
    int w = threadIdx.y;      // 0..3
    int t = w * 64 + lane;
    #pragma unroll
    for (int i = 0; i < 16; i++) az[i * 256 + t] = 0.f;
    __syncthreads();

    int lo = off2d[b * 256], hi = off2d[(b + 1) * 256];
    int len = hi - lo;
    int wlo = lo + (len * w) / 4;
    int whi = lo + (len * (w + 1)) / 4;

    for (int e = wlo; e < whi; e += 64) {
        int m = whi - e;
        if (m > 64) m = 64;
        unsigned ex = 0, ey = 0;
        if (lane < m) { uint2 ev = ebufD[e + lane]; ex = ev.x; ey = ev.y; }
        int j = 0;
        for (; j + 4 <= m; j += 4) {
            unsigned x0 = (unsigned)__shfl((int)ex, j, 64);
            unsigned x1 = (unsigned)__shfl((int)ex, j + 1, 64);
            unsigned x2 = (unsigned)__shfl((int)ex, j + 2, 64);
            unsigned x3 = (unsigned)__shfl((int)ex, j + 3, 64);
            float w0 = __uint_as_float((unsigned)__shfl((int)ey, j, 64));
            float w1 = __uint_as_float((unsigned)__shfl((int)ey, j + 1, 64));
            float w2 = __uint_as_float((unsigned)__shfl((int)ey, j + 2, 64));
            float w3 = __uint_as_float((unsigned)__shfl((int)ey, j + 3, 64));
            float z0 = zin[(x0 & 0xFFFF) * DCH + lane];
            float z1 = zin[(x1 & 0xFFFF) * DCH + lane];
            float z2 = zin[(x2 & 0xFFFF) * DCH + lane];
            float z3 = zin[(x3 & 0xFFFF) * DCH + lane];
            atomicAdd(&az[((x0 >> 16) & 63) * 64 + lane], w0 * z0);
            atomicAdd(&az[((x1 >> 16) & 63) * 64 + lane], w1 * z1);
            atomicAdd(&az[((x2 >> 16) & 63) * 64 + lane], w2 * z2);
            atomicAdd(&az[((x3 >> 16) & 63) * 64 + lane], w3 * z3);
        }
        for (; j < m; j++) {
            unsigned x0 = (unsigned)__shfl((int)ex, j, 64);
            float w0 = __uint_as_float((unsigned)__shfl((int)ey, j, 64));
            float z0 = zin[(x0 & 0xFFFF) * DCH + lane];
            atomicAdd(&az[((x0 >> 16) & 63) * 64 + lane], w0 * z0);
        }
    }
    __syncthreads();

    for (int nd = w; nd < 64; nd += 4) {
        int node = b * 64 + nd;
        if (node >= N) break;
        int idx = node * DCH + lane;
        float azv = az[nd * 64 + lane];
        float zi = zin[idx];
        float k  = azv - zi;
        float xi = x[idx];
        if (pass == 1)      { acc[idx] = k;        zout[idx] = xi + 0.5f * k; }
        else if (pass == 2) { acc[idx] += 2.f * k; zout[idx] = xi + 0.5f * k; }
        else if (pass == 3) { acc[idx] += 2.f * k; zout[idx] = xi + k; }
        else                { zout[idx] = xi + (acc[idx] + k) / 6.0f; }
    }
}

extern "C" void kernel_launch(void* const* d_in, const int* in_sizes, int n_in,
                              void* d_out, int out_size, void* d_ws, size_t ws_size,
                              hipStream_t stream) {
    const float* x   = (const float*)d_in[0];
    const float* att = (const float*)d_in[1];
    const int*   ei  = (const int*)d_in[2];
    const int E = in_sizes[1];
    const int N = in_sizes[0] / DCH;
    const int* src = ei;
    const int* dst = ei + E;

    const int NB    = (N + 63) >> 6;        // 782
    const int NB256 = NB * 256;
    const int NK2   = 2 * NB256;
    // kept <= E - (i0+1): safe capacity
    const int EK = E - (int)((long long)(0.2 * (double)(E - 1))) + 64;

    char* ws = (char*)d_ws;
    size_t off = 0;
    auto alloc = [&](size_t b) { size_t o = off; off += (b + 255) & ~(size_t)255; return o; };
    int*   hist2d = (int*)  (ws + alloc((size_t)GB_HIST * NBINS * 4));
    int*   hist   = (int*)  (ws + alloc((size_t)NBINS * 4));
    int*   csum   = (int*)  (ws + alloc(64 * 4));
    Ctrl*  ctrl   = (Ctrl*) (ws + alloc(256));
    float* cand   = (float*)(ws + alloc((size_t)CAP * 4));
    int*   cntAll = (int*)  (ws + alloc((size_t)NK2 * 4));
    int*   off2d  = (int*)  (ws + alloc(((size_t)NK2 + 1) * 4));
    int*   bsum   = (int*)  (ws + alloc(256 * 4));
    int*   boff   = (int*)  (ws + alloc(256 * 4));
    float* sums   = (float*)(ws + alloc((size_t)N * 4));
    uint2* ebufD  = (uint2*)(ws + alloc((size_t)EK * 8));
    float* ebufSv = (float*)(ws + alloc((size_t)EK * 4));
    unsigned char* ebufSs = (unsigned char*)(ws + alloc((size_t)EK));
    float* zA     = (float*)(ws + alloc((size_t)N * DCH * 4));
    float* acc    = (float*)(ws + alloc((size_t)N * DCH * 4));
    float* out    = (float*)d_out;

    hipMemsetAsync(ctrl, 0, 256, stream);

    // numpy-style quantile index arithmetic (float64)
    double q   = 1.0 - 0.8;
    double pos = q * (double)(E - 1);
    long long i0 = (long long)floor(pos);
    double frac  = pos - (double)i0;
    long long i1 = i0 + 1;
    if (i1 > (long long)E - 1) i1 = (long long)E - 1;

    const int eb = (E + 255) / 256;
    const int nbscan = (NK2 + SCAN_CH - 1) / SCAN_CH;   // 196

    k_hist    <<<GB_HIST, 256, 0, stream>>>(att, E, hist2d);
    k_fold    <<<NBINS / 256, 256, 0, stream>>>(hist2d, hist, csum);
    k_pick    <<<1, 256, 0, stream>>>(hist, csum, ctrl, i0, i1);
    k_collect <<<eb, 256, 0, stream>>>(att, E, ctrl, cand);
    k_finalize<<<1, 256, 0, stream>>>(ctrl, cand, i0, i1, frac);
    k_count   <<<GBC, 256, 0, stream>>>(att, src, dst, E, NB, NB256, ctrl, cntAll);
    k_scan1   <<<nbscan, 256, 0, stream>>>(cntAll, NB, NB256, NK2, bsum);
    k_scan2   <<<1, 256, 0, stream>>>(bsum, nbscan, boff, off2d, NK2);
    k_scan3   <<<nbscan, 256, 0, stream>>>(cntAll, NB, NB256, NK2, boff, off2d);
    k_scatter <<<GBC, 256, 0, stream>>>(att, src, dst, E, NB, NB256, ctrl, off2d,
                                        ebufD, ebufSv, ebufSs);
    k_sums    <<<NB, 256, 0, stream>>>(off2d, NB256, ebufSv, ebufSs, sums, N);
    k_wfix    <<<eb, 256, 0, stream>>>(ebufD, sums, off2d, NB256);

    dim3 blk(64, 4);
    k_spmv<<<NB, blk, 0, stream>>>(off2d, ebufD, x,   x, acc, zA,  N, 1);
    k_spmv<<<NB, blk, 0, stream>>>(off2d, ebufD, zA,  x, acc, out, N, 2);
    k_spmv<<<NB, blk, 0, stream>>>(off2d, ebufD, out, x, acc, zA,  N, 3);
    k_spmv<<<NB, blk, 0, stream>>>(off2d, ebufD, zA,  x, acc, out, N, 4);
}

// Round 5
// 398.935 us; speedup vs baseline: 6.3831x; 6.3831x over previous
//
#include <hip/hip_runtime.h>
#include <math.h>

#define NBINS   16384
#define GB_HIST 128
#define GBC     256     // count/scatter grid blocks
#define CAP     2048
#define DCH     64
#define NBMAX   1024    // max buckets (N <= 65536)
#define SCAN_CH 2048

struct Ctrl {
    double thr;
    int cand_cnt;
    int b0, b1;
    int base0;
    float s0, s1;
};

__device__ __forceinline__ int bin_of(float v) {
    int b = (int)(v * (float)NBINS);
    if (b < 0) b = 0;
    if (b >= NBINS) b = NBINS - 1;
    return b;
}

// ---------- LDS histogram, dense (non-atomic) flush ----------
__global__ void k_hist(const float* __restrict__ att, int E, int* __restrict__ hist2d) {
    __shared__ int lh[NBINS];   // 64 KB
    int t = threadIdx.x;
    for (int b = t; b < NBINS; b += 256) lh[b] = 0;
    __syncthreads();
    for (int i = blockIdx.x * 256 + t; i < E; i += GB_HIST * 256)
        atomicAdd(&lh[bin_of(att[i])], 1);
    __syncthreads();
    for (int b = t; b < NBINS; b += 256)
        hist2d[blockIdx.x * NBINS + b] = lh[b];
}

// 64 blocks x 256: fold 128 partial hists, emit per-256-bin-chunk sums
__global__ void k_fold(const int* __restrict__ hist2d, int* __restrict__ hist,
                       int* __restrict__ csum) {
    __shared__ int sh[4];
    int t = threadIdx.x;
    int j = blockIdx.x * 256 + t;
    int s = 0;
    for (int k = 0; k < GB_HIST; k++) s += hist2d[k * NBINS + j];
    hist[j] = s;
    int r = s;
    for (int off = 32; off > 0; off >>= 1) r += __shfl_down(r, off, 64);
    if ((t & 63) == 0) sh[t >> 6] = r;
    __syncthreads();
    if (t == 0) csum[blockIdx.x] = sh[0] + sh[1] + sh[2] + sh[3];
}

// 1 block: chunk scan (64 chunks) then bin scans -> b0, b1, base0
__global__ void k_pick(const int* __restrict__ hist, const int* __restrict__ csum,
                       Ctrl* ctrl, long long i0, long long i1) {
    __shared__ int sh[256];
    __shared__ int c0s, c1s;
    __shared__ long long e0s, e1s;
    int t = threadIdx.x;
    int v = (t < 64) ? csum[t] : 0;
    sh[t] = v;
    __syncthreads();
    for (int off = 1; off < 256; off <<= 1) {
        int u = (t >= off) ? sh[t - off] : 0;
        __syncthreads(); sh[t] += u; __syncthreads();
    }
    long long excl = (long long)(sh[t] - v);
    if (t < 64) {
        if (i0 >= excl && i0 < excl + v) { c0s = t; e0s = excl; }
        if (i1 >= excl && i1 < excl + v) { c1s = t; e1s = excl; }
    }
    __syncthreads();
    int c0 = c0s, c1 = c1s;
    long long e0 = e0s, e1 = e1s;

    int hv = hist[c0 * 256 + t];
    sh[t] = hv; __syncthreads();
    for (int off = 1; off < 256; off <<= 1) {
        int u = (t >= off) ? sh[t - off] : 0;
        __syncthreads(); sh[t] += u; __syncthreads();
    }
    long long be = e0 + (long long)(sh[t] - hv);
    if (i0 >= be && i0 < be + hv) { ctrl->b0 = c0 * 256 + t; ctrl->base0 = (int)be; }
    __syncthreads();

    hv = hist[c1 * 256 + t];
    sh[t] = hv; __syncthreads();
    for (int off = 1; off < 256; off <<= 1) {
        int u = (t >= off) ? sh[t - off] : 0;
        __syncthreads(); sh[t] += u; __syncthreads();
    }
    be = e1 + (long long)(sh[t] - hv);
    if (i1 >= be && i1 < be + hv) { ctrl->b1 = c1 * 256 + t; }
}

__global__ void k_collect(const float* __restrict__ att, int E,
                          Ctrl* ctrl, float* __restrict__ cand) {
    int b0 = ctrl->b0, b1 = ctrl->b1;
    int i = blockIdx.x * blockDim.x + threadIdx.x;
    int stride = gridDim.x * blockDim.x;
    for (; i < E; i += stride) {
        float v = att[i];
        int b = bin_of(v);
        if (b >= b0 && b <= b1) {
            int idx = atomicAdd(&ctrl->cand_cnt, 1);
            if (idx < CAP) cand[idx] = v;
        }
    }
}

__global__ void k_finalize(Ctrl* ctrl, const float* __restrict__ cand,
                           long long i0, long long i1, double frac) {
    __shared__ float sh[CAP];
    __shared__ float s0s, s1s;
    int n = ctrl->cand_cnt;
    if (n > CAP) n = CAP;
    for (int i = threadIdx.x; i < n; i += blockDim.x) sh[i] = cand[i];
    __syncthreads();
    int r0 = (int)(i0 - (long long)ctrl->base0);
    int r1 = (int)(i1 - (long long)ctrl->base0);
    for (int i = threadIdx.x; i < n; i += blockDim.x) {
        float v = sh[i];
        int rank = 0;
        for (int j = 0; j < n; j++) {
            float u = sh[j];
            rank += (u < v) || (u == v && j < i);
        }
        if (rank == r0) s0s = v;
        if (rank == r1) s1s = v;
    }
    __syncthreads();
    if (threadIdx.x == 0) {
        double a = (double)s0s, b = (double)s1s;
        ctrl->thr = b - (b - a) * (1.0 - frac);   // numpy _lerp, t>=0.5 branch
        ctrl->s0 = s0s; ctrl->s1 = s1s;
    }
}

// ---------- count pass: LDS bucket counters for dst AND src, dense flush ----------
__global__ void k_count(const float* __restrict__ att, const int* __restrict__ src,
                        const int* __restrict__ dst, int E, int NB, int NB256,
                        const Ctrl* __restrict__ ctrl, int* __restrict__ cntAll) {
    __shared__ int lD[NBMAX], lS[NBMAX];
    int t = threadIdx.x;
    for (int b = t; b < NB; b += 256) { lD[b] = 0; lS[b] = 0; }
    __syncthreads();
    double thr = ctrl->thr;
    for (int i = blockIdx.x * 256 + t; i < E; i += GBC * 256) {
        float v = att[i];
        if ((double)v > thr) {
            atomicAdd(&lD[dst[i] >> 6], 1);
            atomicAdd(&lS[src[i] >> 6], 1);
        }
    }
    __syncthreads();
    for (int b = t; b < NB; b += 256) {
        cntAll[blockIdx.x * NB + b]         = lD[b];
        cntAll[NB256 + blockIdx.x * NB + b] = lS[b];
    }
}

// scan domain j in [0, 2*NB256): (half, bucket, blk) -> cntAll[half*NB256 + blk*NB + bucket]
__device__ __forceinline__ int cnt_at(const int* cntAll, int j, int NB, int NB256) {
    int base = 0, r = j;
    if (j >= NB256) { base = NB256; r = j - NB256; }
    return cntAll[base + (r & 255) * NB + (r >> 8)];
}

__global__ void k_scan1(const int* __restrict__ cntAll, int NB, int NB256, int NK2,
                        int* __restrict__ bsum) {
    __shared__ int sh[8];
    int b = blockIdx.x, t = threadIdx.x;
    int j0 = b * SCAN_CH + t * 8;
    int s = 0;
    for (int u = 0; u < 8; u++) {
        int j = j0 + u;
        if (j < NK2) s += cnt_at(cntAll, j, NB, NB256);
    }
    for (int off = 32; off > 0; off >>= 1) s += __shfl_down(s, off, 64);
    if ((t & 63) == 0) sh[t >> 6] = s;
    __syncthreads();
    if (t == 0) bsum[b] = sh[0] + sh[1] + sh[2] + sh[3];
}

__global__ void k_scan2(const int* __restrict__ bsum, int nb,
                        int* __restrict__ boff, int* __restrict__ off2d, int NK2) {
    __shared__ int sh[256];
    int t = threadIdx.x;
    int v = (t < nb) ? bsum[t] : 0;
    sh[t] = v;
    __syncthreads();
    for (int off = 1; off < 256; off <<= 1) {
        int u = (t >= off) ? sh[t - off] : 0;
        __syncthreads(); sh[t] += u; __syncthreads();
    }
    boff[t] = sh[t] - v;
    if (t == 255) off2d[NK2] = sh[255];
}

__global__ void k_scan3(const int* __restrict__ cntAll, int NB, int NB256, int NK2,
                        const int* __restrict__ boff, int* __restrict__ off2d) {
    __shared__ int sh[256];
    int b = blockIdx.x, t = threadIdx.x;
    int j0 = b * SCAN_CH + t * 8;
    int v[8];
    int ts = 0;
    for (int u = 0; u < 8; u++) {
        int j = j0 + u;
        v[u] = (j < NK2) ? cnt_at(cntAll, j, NB, NB256) : 0;
        ts += v[u];
    }
    sh[t] = ts;
    __syncthreads();
    for (int off = 1; off < 256; off <<= 1) {
        int u = (t >= off) ? sh[t - off] : 0;
        __syncthreads(); sh[t] += u; __syncthreads();
    }
    int excl = boff[b] + sh[t] - ts;
    for (int u = 0; u < 8; u++) {
        int j = j0 + u;
        if (j < NK2) off2d[j] = excl;
        excl += v[u];
    }
}

// ---------- scatter into dst-bucketed (src|dlow, v) and src-bucketed (v, slow) ----------
__global__ void k_scatter(const float* __restrict__ att, const int* __restrict__ src,
                          const int* __restrict__ dst, int E, int NB, int NB256,
                          const Ctrl* __restrict__ ctrl, const int* __restrict__ off2d,
                          uint2* __restrict__ ebufD, float* __restrict__ ebufSv,
                          unsigned char* __restrict__ ebufSs) {
    __shared__ int baseD[NBMAX], baseS[NBMAX], fD[NBMAX], fS[NBMAX];
    int t = threadIdx.x;
    int K = off2d[NB256];
    for (int b = t; b < NB; b += 256) {
        baseD[b] = off2d[b * 256 + blockIdx.x];
        baseS[b] = off2d[NB256 + b * 256 + blockIdx.x] - K;
        fD[b] = 0; fS[b] = 0;
    }
    __syncthreads();
    double thr = ctrl->thr;
    for (int i = blockIdx.x * 256 + t; i < E; i += GBC * 256) {
        float v = att[i];
        if ((double)v > thr) {
            int s = src[i], d = dst[i];
            int bD = d >> 6, bS = s >> 6;
            int pD = baseD[bD] + atomicAdd(&fD[bD], 1);
            uint2 ev; ev.x = (unsigned)s | ((unsigned)(d & 63) << 16);
            ev.y = __float_as_uint(v);
            ebufD[pD] = ev;
            int pS = baseS[bS] + atomicAdd(&fS[bS], 1);
            ebufSv[pS] = v;
            ebufSs[pS] = (unsigned char)(s & 63);
        }
    }
}

// per-src-bucket segment sum -> sums[N]
__global__ void k_sums(const int* __restrict__ off2d, int NB256,
                       const float* __restrict__ ebufSv, const unsigned char* __restrict__ ebufSs,
                       float* __restrict__ sums, int N) {
    __shared__ float s64[64];
    int b = blockIdx.x, t = threadIdx.x;
    if (t < 64) s64[t] = 0.f;
    __syncthreads();
    int K = off2d[NB256];
    int lo = off2d[NB256 + b * 256] - K;
    int hi = off2d[NB256 + (b + 1) * 256] - K;
    for (int e = lo + t; e < hi; e += 256)
        atomicAdd(&s64[ebufSs[e]], ebufSv[e]);
    __syncthreads();
    if (t < 64) {
        int node = b * 64 + t;
        if (node < N) sums[node] = s64[t];
    }
}

// ---------- per-bucket LDS counting sort: bucketed ebufD -> per-node CSR + rowp ----------
// Also folds in the weight normalization w = v / (sums[src] + eps).
__global__ __launch_bounds__(256) void k_sort(const int* __restrict__ off2d,
                                              const uint2* __restrict__ ebufD,
                                              const float* __restrict__ sums,
                                              uint2* __restrict__ csr,
                                              int* __restrict__ rowp, int N) {
    __shared__ int cnt[64], base[65], fill[64];
    int b = blockIdx.x, t = threadIdx.x;
    if (t < 64) { cnt[t] = 0; fill[t] = 0; }
    __syncthreads();
    int lo = off2d[b * 256], hi = off2d[(b + 1) * 256];
    for (int e = lo + t; e < hi; e += 256)
        atomicAdd(&cnt[(ebufD[e].x >> 16) & 63], 1);
    __syncthreads();
    if (t == 0) {
        int s = 0;
        for (int i = 0; i < 64; i++) { base[i] = s; s += cnt[i]; }
        base[64] = s;
    }
    __syncthreads();
    if (t <= 64) {
        int node = b * 64 + t;
        if (node <= N) rowp[node] = lo + base[t];
    }
    for (int e = lo + t; e < hi; e += 256) {
        uint2 ev = ebufD[e];
        int dl = (ev.x >> 16) & 63;
        int pos = lo + base[dl] + atomicAdd(&fill[dl], 1);
        int s = ev.x & 0xFFFF;
        float w = __uint_as_float(ev.y) / (sums[s] + 1e-16f);
        uint2 o; o.x = ev.x; o.y = __float_as_uint(w);
        csr[pos] = o;
    }
}

// ---------- spmv: one wave per dst node, per-node CSR, fused RK4 epilogue ----------
__global__ __launch_bounds__(256) void k_spmv(
    const int* __restrict__ rowp, const uint2* __restrict__ csr,
    const float* __restrict__ zin, const float* __restrict__ x,
    float* __restrict__ acc, float* __restrict__ zout, int N, int pass)
{
    int node = blockIdx.x * 4 + threadIdx.y;
    if (node >= N) return;
    int lane = threadIdx.x;
    int beg = rowp[node], end = rowp[node + 1];

    float az0 = 0.f, az1 = 0.f, az2 = 0.f, az3 = 0.f;
    for (int e = beg; e < end; e += 64) {
        int m = end - e;
        if (m > 64) m = 64;
        unsigned ex = 0, ey = 0;
        if (lane < m) { uint2 ev = csr[e + lane]; ex = ev.x; ey = ev.y; }
        int j = 0;
        for (; j + 4 <= m; j += 4) {
            unsigned x0 = (unsigned)__shfl((int)ex, j,     64);
            unsigned x1 = (unsigned)__shfl((int)ex, j + 1, 64);
            unsigned x2 = (unsigned)__shfl((int)ex, j + 2, 64);
            unsigned x3 = (unsigned)__shfl((int)ex, j + 3, 64);
            float w0 = __uint_as_float((unsigned)__shfl((int)ey, j,     64));
            float w1 = __uint_as_float((unsigned)__shfl((int)ey, j + 1, 64));
            float w2 = __uint_as_float((unsigned)__shfl((int)ey, j + 2, 64));
            float w3 = __uint_as_float((unsigned)__shfl((int)ey, j + 3, 64));
            az0 = fmaf(w0, zin[(x0 & 0xFFFF) * DCH + lane], az0);
            az1 = fmaf(w1, zin[(x1 & 0xFFFF) * DCH + lane], az1);
            az2 = fmaf(w2, zin[(x2 & 0xFFFF) * DCH + lane], az2);
            az3 = fmaf(w3, zin[(x3 & 0xFFFF) * DCH + lane], az3);
        }
        for (; j < m; j++) {
            unsigned x0 = (unsigned)__shfl((int)ex, j, 64);
            float w0 = __uint_as_float((unsigned)__shfl((int)ey, j, 64));
            az0 = fmaf(w0, zin[(x0 & 0xFFFF) * DCH + lane], az0);
        }
    }
    float az = (az0 + az1) + (az2 + az3);

    int idx = node * DCH + lane;
    float zi = zin[idx];
    float k  = az - zi;
    float xi = x[idx];
    if (pass == 1)      { acc[idx] = k;        zout[idx] = xi + 0.5f * k; }
    else if (pass == 2) { acc[idx] += 2.f * k; zout[idx] = xi + 0.5f * k; }
    else if (pass == 3) { acc[idx] += 2.f * k; zout[idx] = xi + k; }
    else                { zout[idx] = xi + (acc[idx] + k) / 6.0f; }
}

extern "C" void kernel_launch(void* const* d_in, const int* in_sizes, int n_in,
                              void* d_out, int out_size, void* d_ws, size_t ws_size,
                              hipStream_t stream) {
    const float* x   = (const float*)d_in[0];
    const float* att = (const float*)d_in[1];
    const int*   ei  = (const int*)d_in[2];
    const int E = in_sizes[1];
    const int N = in_sizes[0] / DCH;     // NOTE: src packed in 16 bits -> requires N <= 65536
    const int* src = ei;
    const int* dst = ei + E;

    const int NB    = (N + 63) >> 6;
    const int NB256 = NB * 256;
    const int NK2   = 2 * NB256;
    const int EK = E - (int)((long long)(0.2 * (double)(E - 1))) + 64;

    char* ws = (char*)d_ws;
    size_t off = 0;
    auto alloc = [&](size_t b) { size_t o = off; off += (b + 255) & ~(size_t)255; return o; };
    int*   hist2d = (int*)  (ws + alloc((size_t)GB_HIST * NBINS * 4));
    int*   hist   = (int*)  (ws + alloc((size_t)NBINS * 4));
    int*   csum   = (int*)  (ws + alloc(64 * 4));
    Ctrl*  ctrl   = (Ctrl*) (ws + alloc(256));
    float* cand   = (float*)(ws + alloc((size_t)CAP * 4));
    int*   cntAll = (int*)  (ws + alloc((size_t)NK2 * 4));
    int*   off2d  = (int*)  (ws + alloc(((size_t)NK2 + 1) * 4));
    int*   bsum   = (int*)  (ws + alloc(256 * 4));
    int*   boff   = (int*)  (ws + alloc(256 * 4));
    float* sums   = (float*)(ws + alloc((size_t)N * 4));
    int*   rowp   = (int*)  (ws + alloc(((size_t)N + 1) * 4));
    uint2* ebufD  = (uint2*)(ws + alloc((size_t)EK * 8));
    uint2* csr    = (uint2*)(ws + alloc((size_t)EK * 8));
    float* ebufSv = (float*)(ws + alloc((size_t)EK * 4));
    unsigned char* ebufSs = (unsigned char*)(ws + alloc((size_t)EK));
    float* zA     = (float*)(ws + alloc((size_t)N * DCH * 4));
    float* acc    = (float*)(ws + alloc((size_t)N * DCH * 4));
    float* out    = (float*)d_out;

    hipMemsetAsync(ctrl, 0, 256, stream);

    // numpy-style quantile index arithmetic (float64)
    double q   = 1.0 - 0.8;
    double pos = q * (double)(E - 1);
    long long i0 = (long long)floor(pos);
    double frac  = pos - (double)i0;
    long long i1 = i0 + 1;
    if (i1 > (long long)E - 1) i1 = (long long)E - 1;

    const int eb = (E + 255) / 256;
    const int nbscan = (NK2 + SCAN_CH - 1) / SCAN_CH;

    k_hist    <<<GB_HIST, 256, 0, stream>>>(att, E, hist2d);
    k_fold    <<<NBINS / 256, 256, 0, stream>>>(hist2d, hist, csum);
    k_pick    <<<1, 256, 0, stream>>>(hist, csum, ctrl, i0, i1);
    k_collect <<<eb, 256, 0, stream>>>(att, E, ctrl, cand);
    k_finalize<<<1, 256, 0, stream>>>(ctrl, cand, i0, i1, frac);
    k_count   <<<GBC, 256, 0, stream>>>(att, src, dst, E, NB, NB256, ctrl, cntAll);
    k_scan1   <<<nbscan, 256, 0, stream>>>(cntAll, NB, NB256, NK2, bsum);
    k_scan2   <<<1, 256, 0, stream>>>(bsum, nbscan, boff, off2d, NK2);
    k_scan3   <<<nbscan, 256, 0, stream>>>(cntAll, NB, NB256, NK2, boff, off2d);
    k_scatter <<<GBC, 256, 0, stream>>>(att, src, dst, E, NB, NB256, ctrl, off2d,
                                        ebufD, ebufSv, ebufSs);
    k_sums    <<<NB, 256, 0, stream>>>(off2d, NB256, ebufSv, ebufSs, sums, N);
    k_sort    <<<NB, 256, 0, stream>>>(off2d, ebufD, sums, csr, rowp, N);

    dim3 blk(64, 4);
    int nb = (N + 3) / 4;
    k_spmv<<<nb, blk, 0, stream>>>(rowp, csr, x,   x, acc, zA,  N, 1);
    k_spmv<<<nb, blk, 0, stream>>>(rowp, csr, zA,  x, acc, out, N, 2);
    k_spmv<<<nb, blk, 0, stream>>>(rowp, csr, out, x, acc, zA,  N, 3);
    k_spmv<<<nb, blk, 0, stream>>>(rowp, csr, zA,  x, acc, out, N, 4);
}

// Round 6
// 373.212 us; speedup vs baseline: 6.8230x; 1.0689x over previous
//
#include <hip/hip_runtime.h>
#include <hip/hip_fp16.h>
#include <math.h>

#define NBINS   4096
#define GB_HIST 128
#define GBC     256     // count/scatter grid blocks
#define CAP     2048
#define DCH     64
#define NBMAX   1024    // max buckets (N <= 65536)
#define SCAN_CH 2048

struct Ctrl {
    double thr;
    int cand_cnt;
    int b0, b1;
    int base0;
    float s0, s1;
};

__device__ __forceinline__ int bin_of(float v) {
    int b = (int)(v * (float)NBINS);
    if (b < 0) b = 0;
    if (b >= NBINS) b = NBINS - 1;
    return b;
}

// ---------- LDS histogram, dense (non-atomic) flush ----------
__global__ void k_hist(const float* __restrict__ att, int E, int* __restrict__ hist2d) {
    __shared__ int lh[NBINS];   // 16 KB
    int t = threadIdx.x;
    for (int b = t; b < NBINS; b += 256) lh[b] = 0;
    __syncthreads();
    for (int i = blockIdx.x * 256 + t; i < E; i += GB_HIST * 256)
        atomicAdd(&lh[bin_of(att[i])], 1);
    __syncthreads();
    for (int b = t; b < NBINS; b += 256)
        hist2d[blockIdx.x * NBINS + b] = lh[b];
}

// 16 blocks x 256: fold 128 partial hists, emit per-256-bin-chunk sums
__global__ void k_fold(const int* __restrict__ hist2d, int* __restrict__ hist,
                       int* __restrict__ csum) {
    __shared__ int sh[4];
    int t = threadIdx.x;
    int j = blockIdx.x * 256 + t;
    int s = 0;
    for (int k = 0; k < GB_HIST; k++) s += hist2d[k * NBINS + j];
    hist[j] = s;
    int r = s;
    for (int off = 32; off > 0; off >>= 1) r += __shfl_down(r, off, 64);
    if ((t & 63) == 0) sh[t >> 6] = r;
    __syncthreads();
    if (t == 0) csum[blockIdx.x] = sh[0] + sh[1] + sh[2] + sh[3];
}

// 1 block: chunk scan (16 chunks) then bin scans -> b0, b1, base0
__global__ void k_pick(const int* __restrict__ hist, const int* __restrict__ csum,
                       Ctrl* ctrl, long long i0, long long i1) {
    __shared__ int sh[256];
    __shared__ int c0s, c1s;
    __shared__ long long e0s, e1s;
    int t = threadIdx.x;
    int v = (t < NBINS / 256) ? csum[t] : 0;
    sh[t] = v;
    __syncthreads();
    for (int off = 1; off < 256; off <<= 1) {
        int u = (t >= off) ? sh[t - off] : 0;
        __syncthreads(); sh[t] += u; __syncthreads();
    }
    long long excl = (long long)(sh[t] - v);
    if (t < NBINS / 256) {
        if (i0 >= excl && i0 < excl + v) { c0s = t; e0s = excl; }
        if (i1 >= excl && i1 < excl + v) { c1s = t; e1s = excl; }
    }
    __syncthreads();
    int c0 = c0s, c1 = c1s;
    long long e0 = e0s, e1 = e1s;

    int hv = hist[c0 * 256 + t];
    sh[t] = hv; __syncthreads();
    for (int off = 1; off < 256; off <<= 1) {
        int u = (t >= off) ? sh[t - off] : 0;
        __syncthreads(); sh[t] += u; __syncthreads();
    }
    long long be = e0 + (long long)(sh[t] - hv);
    if (i0 >= be && i0 < be + hv) { ctrl->b0 = c0 * 256 + t; ctrl->base0 = (int)be; }
    __syncthreads();

    hv = hist[c1 * 256 + t];
    sh[t] = hv; __syncthreads();
    for (int off = 1; off < 256; off <<= 1) {
        int u = (t >= off) ? sh[t - off] : 0;
        __syncthreads(); sh[t] += u; __syncthreads();
    }
    be = e1 + (long long)(sh[t] - hv);
    if (i1 >= be && i1 < be + hv) { ctrl->b1 = c1 * 256 + t; }
}

__global__ void k_collect(const float* __restrict__ att, int E,
                          Ctrl* ctrl, float* __restrict__ cand) {
    int b0 = ctrl->b0, b1 = ctrl->b1;
    int i = blockIdx.x * blockDim.x + threadIdx.x;
    int stride = gridDim.x * blockDim.x;
    for (; i < E; i += stride) {
        float v = att[i];
        int b = bin_of(v);
        if (b >= b0 && b <= b1) {
            int idx = atomicAdd(&ctrl->cand_cnt, 1);
            if (idx < CAP) cand[idx] = v;
        }
    }
}

__global__ void k_finalize(Ctrl* ctrl, const float* __restrict__ cand,
                           long long i0, long long i1, double frac) {
    __shared__ float sh[CAP];
    __shared__ float s0s, s1s;
    int n = ctrl->cand_cnt;
    if (n > CAP) n = CAP;
    for (int i = threadIdx.x; i < n; i += blockDim.x) sh[i] = cand[i];
    __syncthreads();
    int r0 = (int)(i0 - (long long)ctrl->base0);
    int r1 = (int)(i1 - (long long)ctrl->base0);
    for (int i = threadIdx.x; i < n; i += blockDim.x) {
        float v = sh[i];
        int rank = 0;
        for (int j = 0; j < n; j++) {
            float u = sh[j];
            rank += (u < v) || (u == v && j < i);
        }
        if (rank == r0) s0s = v;
        if (rank == r1) s1s = v;
    }
    __syncthreads();
    if (threadIdx.x == 0) {
        double a = (double)s0s, b = (double)s1s;
        ctrl->thr = b - (b - a) * (1.0 - frac);   // numpy _lerp, t>=0.5 branch
        ctrl->s0 = s0s; ctrl->s1 = s1s;
    }
}

// ---------- count pass: LDS bucket counters for dst AND src, dense flush ----------
__global__ void k_count(const float* __restrict__ att, const int* __restrict__ src,
                        const int* __restrict__ dst, int E, int NB, int NB256,
                        const Ctrl* __restrict__ ctrl, int* __restrict__ cntAll) {
    __shared__ int lD[NBMAX], lS[NBMAX];
    int t = threadIdx.x;
    for (int b = t; b < NB; b += 256) { lD[b] = 0; lS[b] = 0; }
    __syncthreads();
    double thr = ctrl->thr;
    for (int i = blockIdx.x * 256 + t; i < E; i += GBC * 256) {
        float v = att[i];
        if ((double)v > thr) {
            atomicAdd(&lD[dst[i] >> 6], 1);
            atomicAdd(&lS[src[i] >> 6], 1);
        }
    }
    __syncthreads();
    for (int b = t; b < NB; b += 256) {
        cntAll[blockIdx.x * NB + b]         = lD[b];
        cntAll[NB256 + blockIdx.x * NB + b] = lS[b];
    }
}

// scan domain j in [0, 2*NB256): (half, bucket, blk) -> cntAll[half*NB256 + blk*NB + bucket]
__device__ __forceinline__ int cnt_at(const int* cntAll, int j, int NB, int NB256) {
    int base = 0, r = j;
    if (j >= NB256) { base = NB256; r = j - NB256; }
    return cntAll[base + (r & 255) * NB + (r >> 8)];
}

__global__ void k_scan1(const int* __restrict__ cntAll, int NB, int NB256, int NK2,
                        int* __restrict__ bsum) {
    __shared__ int sh[8];
    int b = blockIdx.x, t = threadIdx.x;
    int j0 = b * SCAN_CH + t * 8;
    int s = 0;
    for (int u = 0; u < 8; u++) {
        int j = j0 + u;
        if (j < NK2) s += cnt_at(cntAll, j, NB, NB256);
    }
    for (int off = 32; off > 0; off >>= 1) s += __shfl_down(s, off, 64);
    if ((t & 63) == 0) sh[t >> 6] = s;
    __syncthreads();
    if (t == 0) bsum[b] = sh[0] + sh[1] + sh[2] + sh[3];
}

__global__ void k_scan2(const int* __restrict__ bsum, int nb,
                        int* __restrict__ boff, int* __restrict__ off2d, int NK2) {
    __shared__ int sh[256];
    int t = threadIdx.x;
    int v = (t < nb) ? bsum[t] : 0;
    sh[t] = v;
    __syncthreads();
    for (int off = 1; off < 256; off <<= 1) {
        int u = (t >= off) ? sh[t - off] : 0;
        __syncthreads(); sh[t] += u; __syncthreads();
    }
    boff[t] = sh[t] - v;
    if (t == 255) off2d[NK2] = sh[255];
}

__global__ void k_scan3(const int* __restrict__ cntAll, int NB, int NB256, int NK2,
                        const int* __restrict__ boff, int* __restrict__ off2d) {
    __shared__ int sh[256];
    int b = blockIdx.x, t = threadIdx.x;
    int j0 = b * SCAN_CH + t * 8;
    int v[8];
    int ts = 0;
    for (int u = 0; u < 8; u++) {
        int j = j0 + u;
        v[u] = (j < NK2) ? cnt_at(cntAll, j, NB, NB256) : 0;
        ts += v[u];
    }
    sh[t] = ts;
    __syncthreads();
    for (int off = 1; off < 256; off <<= 1) {
        int u = (t >= off) ? sh[t - off] : 0;
        __syncthreads(); sh[t] += u; __syncthreads();
    }
    int excl = boff[b] + sh[t] - ts;
    for (int u = 0; u < 8; u++) {
        int j = j0 + u;
        if (j < NK2) off2d[j] = excl;
        excl += v[u];
    }
}

// ---------- scatter into dst-bucketed (src|dlow, v) and src-bucketed (v, slow) ----------
__global__ void k_scatter(const float* __restrict__ att, const int* __restrict__ src,
                          const int* __restrict__ dst, int E, int NB, int NB256,
                          const Ctrl* __restrict__ ctrl, const int* __restrict__ off2d,
                          uint2* __restrict__ ebufD, float* __restrict__ ebufSv,
                          unsigned char* __restrict__ ebufSs) {
    __shared__ int baseD[NBMAX], baseS[NBMAX], fD[NBMAX], fS[NBMAX];
    int t = threadIdx.x;
    int K = off2d[NB256];
    for (int b = t; b < NB; b += 256) {
        baseD[b] = off2d[b * 256 + blockIdx.x];
        baseS[b] = off2d[NB256 + b * 256 + blockIdx.x] - K;
        fD[b] = 0; fS[b] = 0;
    }
    __syncthreads();
    double thr = ctrl->thr;
    for (int i = blockIdx.x * 256 + t; i < E; i += GBC * 256) {
        float v = att[i];
        if ((double)v > thr) {
            int s = src[i], d = dst[i];
            int bD = d >> 6, bS = s >> 6;
            int pD = baseD[bD] + atomicAdd(&fD[bD], 1);
            uint2 ev; ev.x = (unsigned)s | ((unsigned)(d & 63) << 16);
            ev.y = __float_as_uint(v);
            ebufD[pD] = ev;
            int pS = baseS[bS] + atomicAdd(&fS[bS], 1);
            ebufSv[pS] = v;
            ebufSs[pS] = (unsigned char)(s & 63);
        }
    }
}

// per-src-bucket segment sum -> rsums[N] = 1/(sum+eps); also emit xh = f16(x*rsum)
__global__ void k_sums(const int* __restrict__ off2d, int NB256,
                       const float* __restrict__ ebufSv, const unsigned char* __restrict__ ebufSs,
                       const float* __restrict__ x,
                       float* __restrict__ rsums, __half* __restrict__ xh, int N) {
    __shared__ float s64[64];
    __shared__ float r64[64];
    int b = blockIdx.x, t = threadIdx.x;
    if (t < 64) s64[t] = 0.f;
    __syncthreads();
    int K = off2d[NB256];
    int lo = off2d[NB256 + b * 256] - K;
    int hi = off2d[NB256 + (b + 1) * 256] - K;
    for (int e = lo + t; e < hi; e += 256)
        atomicAdd(&s64[ebufSs[e]], ebufSv[e]);
    __syncthreads();
    if (t < 64) {
        float r = 1.f / (s64[t] + 1e-16f);
        r64[t] = r;
        int node = b * 64 + t;
        if (node < N) rsums[node] = r;
    }
    __syncthreads();
    int base = b * 64 * DCH;
    for (int i = t; i < 64 * DCH; i += 256) {
        int node = b * 64 + (i >> 6);
        if (node < N) xh[base + i] = __float2half(x[base + i] * r64[i >> 6]);
    }
}

// ---------- per-bucket LDS counting sort: bucketed ebufD -> per-node packed CSR ----------
// csr entry: src (low 16) | f16(raw v) (high 16). No normalization here.
__global__ __launch_bounds__(256) void k_sort(const int* __restrict__ off2d,
                                              const uint2* __restrict__ ebufD,
                                              unsigned* __restrict__ csr,
                                              int* __restrict__ rowp, int N) {
    __shared__ int cnt[64], base[65], fill[64];
    int b = blockIdx.x, t = threadIdx.x;
    if (t < 64) { cnt[t] = 0; fill[t] = 0; }
    __syncthreads();
    int lo = off2d[b * 256], hi = off2d[(b + 1) * 256];
    for (int e = lo + t; e < hi; e += 256)
        atomicAdd(&cnt[(ebufD[e].x >> 16) & 63], 1);
    __syncthreads();
    if (t == 0) {
        int s = 0;
        for (int i = 0; i < 64; i++) { base[i] = s; s += cnt[i]; }
        base[64] = s;
    }
    __syncthreads();
    if (t <= 64) {
        int node = b * 64 + t;
        if (node <= N) rowp[node] = lo + base[t];
    }
    for (int e = lo + t; e < hi; e += 256) {
        uint2 ev = ebufD[e];
        int dl = (ev.x >> 16) & 63;
        int pos = lo + base[dl] + atomicAdd(&fill[dl], 1);
        unsigned hb = (unsigned)__half_as_ushort(__float2half(__uint_as_float(ev.y)));
        csr[pos] = (ev.x & 0xFFFFu) | (hb << 16);
    }
}

// ---------- spmv: one wave per dst node, packed CSR, f16 gather table ----------
// pass1: zprev=x;  z1 = x + 0.5(az-x);  hout = f16(z1*rsum)
// pass2: z2 = x + 0.5(az-z1)
// pass3: z3 = x + (az-z2)
// pass4: out = (az + 2*z1 + 4*z2 + z3 - 2x)/6        (za=z1, zb=z2, zprev=z3)
__global__ __launch_bounds__(256) void k_spmv(
    const int* __restrict__ rowp, const unsigned* __restrict__ csr,
    const __half* __restrict__ hin, __half* __restrict__ hout,
    const float* __restrict__ rsums, const float* __restrict__ x,
    const float* __restrict__ zprev, float* __restrict__ zout,
    const float* __restrict__ za, const float* __restrict__ zb,
    int N, int pass)
{
    int node = blockIdx.x * 4 + threadIdx.y;
    if (node >= N) return;
    int lane = threadIdx.x;
    int beg = rowp[node], end = rowp[node + 1];

    float a0 = 0.f, a1 = 0.f, a2 = 0.f, a3 = 0.f;
    float a4 = 0.f, a5 = 0.f, a6 = 0.f, a7 = 0.f;
    for (int e = beg; e < end; e += 64) {
        int m = end - e;
        if (m > 64) m = 64;
        unsigned ev = 0;
        if (lane < m) ev = csr[e + lane];
        int j = 0;
        for (; j + 8 <= m; j += 8) {
            unsigned e0 = (unsigned)__shfl((int)ev, j,     64);
            unsigned e1 = (unsigned)__shfl((int)ev, j + 1, 64);
            unsigned e2 = (unsigned)__shfl((int)ev, j + 2, 64);
            unsigned e3 = (unsigned)__shfl((int)ev, j + 3, 64);
            unsigned e4 = (unsigned)__shfl((int)ev, j + 4, 64);
            unsigned e5 = (unsigned)__shfl((int)ev, j + 5, 64);
            unsigned e6 = (unsigned)__shfl((int)ev, j + 6, 64);
            unsigned e7 = (unsigned)__shfl((int)ev, j + 7, 64);
            float z0 = __half2float(hin[(e0 & 0xFFFFu) * DCH + lane]);
            float z1 = __half2float(hin[(e1 & 0xFFFFu) * DCH + lane]);
            float z2 = __half2float(hin[(e2 & 0xFFFFu) * DCH + lane]);
            float z3 = __half2float(hin[(e3 & 0xFFFFu) * DCH + lane]);
            float z4 = __half2float(hin[(e4 & 0xFFFFu) * DCH + lane]);
            float z5 = __half2float(hin[(e5 & 0xFFFFu) * DCH + lane]);
            float z6 = __half2float(hin[(e6 & 0xFFFFu) * DCH + lane]);
            float z7 = __half2float(hin[(e7 & 0xFFFFu) * DCH + lane]);
            a0 = fmaf(__half2float(__ushort_as_half((unsigned short)(e0 >> 16))), z0, a0);
            a1 = fmaf(__half2float(__ushort_as_half((unsigned short)(e1 >> 16))), z1, a1);
            a2 = fmaf(__half2float(__ushort_as_half((unsigned short)(e2 >> 16))), z2, a2);
            a3 = fmaf(__half2float(__ushort_as_half((unsigned short)(e3 >> 16))), z3, a3);
            a4 = fmaf(__half2float(__ushort_as_half((unsigned short)(e4 >> 16))), z4, a4);
            a5 = fmaf(__half2float(__ushort_as_half((unsigned short)(e5 >> 16))), z5, a5);
            a6 = fmaf(__half2float(__ushort_as_half((unsigned short)(e6 >> 16))), z6, a6);
            a7 = fmaf(__half2float(__ushort_as_half((unsigned short)(e7 >> 16))), z7, a7);
        }
        for (; j < m; j++) {
            unsigned e0 = (unsigned)__shfl((int)ev, j, 64);
            float z0 = __half2float(hin[(e0 & 0xFFFFu) * DCH + lane]);
            a0 = fmaf(__half2float(__ushort_as_half((unsigned short)(e0 >> 16))), z0, a0);
        }
    }
    float az = ((a0 + a1) + (a2 + a3)) + ((a4 + a5) + (a6 + a7));

    int idx = node * DCH + lane;
    float k = az - zprev[idx];
    if (pass <= 2) {
        float zo = x[idx] + 0.5f * k;
        zout[idx] = zo;
        hout[idx] = __float2half(zo * rsums[node]);
    } else if (pass == 3) {
        float zo = x[idx] + k;
        zout[idx] = zo;
        hout[idx] = __float2half(zo * rsums[node]);
    } else {
        zout[idx] = (az + 2.f * za[idx] + 4.f * zb[idx] + zprev[idx] - 2.f * x[idx]) * (1.0f / 6.0f);
    }
}

extern "C" void kernel_launch(void* const* d_in, const int* in_sizes, int n_in,
                              void* d_out, int out_size, void* d_ws, size_t ws_size,
                              hipStream_t stream) {
    const float* x   = (const float*)d_in[0];
    const float* att = (const float*)d_in[1];
    const int*   ei  = (const int*)d_in[2];
    const int E = in_sizes[1];
    const int N = in_sizes[0] / DCH;     // NOTE: src packed in 16 bits -> requires N <= 65536
    const int* src = ei;
    const int* dst = ei + E;

    const int NB    = (N + 63) >> 6;
    const int NB256 = NB * 256;
    const int NK2   = 2 * NB256;
    const int EK = E - (int)((long long)(0.2 * (double)(E - 1))) + 64;

    char* ws = (char*)d_ws;
    size_t off = 0;
    auto alloc = [&](size_t b) { size_t o = off; off += (b + 255) & ~(size_t)255; return o; };
    int*    hist2d = (int*)   (ws + alloc((size_t)GB_HIST * NBINS * 4));
    int*    hist   = (int*)   (ws + alloc((size_t)NBINS * 4));
    int*    csum   = (int*)   (ws + alloc(64 * 4));
    Ctrl*   ctrl   = (Ctrl*)  (ws + alloc(256));
    float*  cand   = (float*) (ws + alloc((size_t)CAP * 4));
    int*    cntAll = (int*)   (ws + alloc((size_t)NK2 * 4));
    int*    off2d  = (int*)   (ws + alloc(((size_t)NK2 + 1) * 4));
    int*    bsum   = (int*)   (ws + alloc(256 * 4));
    int*    boff   = (int*)   (ws + alloc(256 * 4));
    float*  rsums  = (float*) (ws + alloc((size_t)N * 4));
    int*    rowp   = (int*)   (ws + alloc(((size_t)N + 1) * 4));
    uint2*  ebufD  = (uint2*) (ws + alloc((size_t)EK * 8));
    unsigned* csr32= (unsigned*)(ws + alloc((size_t)EK * 4));
    float*  ebufSv = (float*) (ws + alloc((size_t)EK * 4));
    unsigned char* ebufSs = (unsigned char*)(ws + alloc((size_t)EK));
    float*  z1     = (float*) (ws + alloc((size_t)N * DCH * 4));
    float*  z2     = (float*) (ws + alloc((size_t)N * DCH * 4));
    float*  z3     = (float*) (ws + alloc((size_t)N * DCH * 4));
    __half* h0     = (__half*)(ws + alloc((size_t)N * DCH * 2));
    __half* h1     = (__half*)(ws + alloc((size_t)N * DCH * 2));
    float*  out    = (float*)d_out;

    hipMemsetAsync(ctrl, 0, 256, stream);

    // numpy-style quantile index arithmetic (float64)
    double q   = 1.0 - 0.8;
    double pos = q * (double)(E - 1);
    long long i0 = (long long)floor(pos);
    double frac  = pos - (double)i0;
    long long i1 = i0 + 1;
    if (i1 > (long long)E - 1) i1 = (long long)E - 1;

    const int eb = (E + 255) / 256;
    const int nbscan = (NK2 + SCAN_CH - 1) / SCAN_CH;

    k_hist    <<<GB_HIST, 256, 0, stream>>>(att, E, hist2d);
    k_fold    <<<NBINS / 256, 256, 0, stream>>>(hist2d, hist, csum);
    k_pick    <<<1, 256, 0, stream>>>(hist, csum, ctrl, i0, i1);
    k_collect <<<eb, 256, 0, stream>>>(att, E, ctrl, cand);
    k_finalize<<<1, 256, 0, stream>>>(ctrl, cand, i0, i1, frac);
    k_count   <<<GBC, 256, 0, stream>>>(att, src, dst, E, NB, NB256, ctrl, cntAll);
    k_scan1   <<<nbscan, 256, 0, stream>>>(cntAll, NB, NB256, NK2, bsum);
    k_scan2   <<<1, 256, 0, stream>>>(bsum, nbscan, boff, off2d, NK2);
    k_scan3   <<<nbscan, 256, 0, stream>>>(cntAll, NB, NB256, NK2, boff, off2d);
    k_scatter <<<GBC, 256, 0, stream>>>(att, src, dst, E, NB, NB256, ctrl, off2d,
                                        ebufD, ebufSv, ebufSs);
    k_sums    <<<NB, 256, 0, stream>>>(off2d, NB256, ebufSv, ebufSs, x, rsums, h0, N);
    k_sort    <<<NB, 256, 0, stream>>>(off2d, ebufD, csr32, rowp, N);

    dim3 blk(64, 4);
    int nb = (N + 3) / 4;
    k_spmv<<<nb, blk, 0, stream>>>(rowp, csr32, h0, h1, rsums, x, x,  z1, nullptr, nullptr, N, 1);
    k_spmv<<<nb, blk, 0, stream>>>(rowp, csr32, h1, h0, rsums, x, z1, z2, nullptr, nullptr, N, 2);
    k_spmv<<<nb, blk, 0, stream>>>(rowp, csr32, h0, h1, rsums, x, z2, z3, nullptr, nullptr, N, 3);
    k_spmv<<<nb, blk, 0, stream>>>(rowp, csr32, h1, nullptr, rsums, x, z3, out, z1, z2, N, 4);
}